// Round 2
// baseline (249.485 us; speedup 1.0000x reference)
//
#include <hip/hip_runtime.h>

// DisMaxLossFirstPart: logits = -|ds|*(dist + mean_c(dist)) / temp
// dist[b,c] = sqrt(max(1 - <fn_b, pn_c>, 0)), fn/pn L2-normalized rows.
// B=32768, C=1000, F=256. fp32 in/out; bf16 MFMA internally.
//
// Design (round 2): single fused kernel, 32 rows/block, 4 waves each owning
// 256 cols. A-frags built in-register from raw fp32 features (norm fused).
// Two GEMM passes over L2-resident prototypes: pass 1 accumulates row dist
// sums (registers + 512B LDS cross-wave reduce), pass 2 recomputes dist and
// writes final logits. No 64KB LDS stripe -> occupancy no longer LDS-capped.
// Prototypes staged bf16 in a fragment-ready permuted layout so every B-frag
// load is one coalesced 1KB dwordx4 per wave.

typedef __attribute__((ext_vector_type(8))) short short8;
typedef __attribute__((ext_vector_type(4))) float f32x4;

union U16 { uint4 u4; short8 s8; };

static __device__ __forceinline__ unsigned short f2bf(float x){
  union { float f; unsigned u; } v; v.f = x;
  unsigned r = v.u + 0x7fffu + ((v.u >> 16) & 1u);   // RNE
  return (unsigned short)(r >> 16);
}

#define CPAD 1024          // prototype rows padded to 1024
#define NTILES (CPAD/16)   // 64 column tiles of 16

// Normalize prototypes [C x 256] fp32 -> bf16 in fragment-ready permuted
// layout: 16B chunk index (t*8 + s)*64 + lane, lane = quad*16 + l16, holding
// pn[t*16 + l16][quad*8 + s*32 .. +8]. Rows >= C written as zeros.
// One wave per row; lane l holds elements 4l..4l+3.
__global__ void norm_protos_kernel(const float* __restrict__ src,
                                   unsigned short* __restrict__ dst, int C)
{
  const int wave = threadIdx.x >> 6;
  const int lane = threadIdx.x & 63;
  const int row  = blockIdx.x * 4 + wave;     // 0..1023
  const int t    = row >> 4;
  const int l16  = row & 15;
  const int s    = lane >> 3;                 // element e=4l: s = e>>5
  const int quad = (lane >> 1) & 3;           // quad = (e>>3)&3
  const int j    = (lane & 1) * 4;            // j = e&7 in {0,4}

  ushort4 o = {0, 0, 0, 0};
  if (row < C){
    const float4 v = *(const float4*)(src + row * 256 + lane * 4);
    float ss = v.x*v.x + v.y*v.y + v.z*v.z + v.w*v.w;
    #pragma unroll
    for (int off = 32; off; off >>= 1) ss += __shfl_xor(ss, off);
    const float inv = 1.0f / fmaxf(sqrtf(ss), 1e-12f);
    o.x = f2bf(v.x * inv); o.y = f2bf(v.y * inv);
    o.z = f2bf(v.z * inv); o.w = f2bf(v.w * inv);
  }
  // chunk = (t*8+s)*64 + quad*16 + l16 ; each chunk is 8 ushorts; j selects half
  *(ushort4*)(dst + ((size_t)((t*8 + s)*64 + quad*16 + l16))*8 + j) = o;
}

__global__ __launch_bounds__(256)
void fused_kernel(const float* __restrict__ feats,
                  const unsigned short* __restrict__ pnw,
                  const float* __restrict__ ds,
                  const float* __restrict__ temp,
                  float* __restrict__ out, int C)
{
  __shared__ float wsum[4][32];   // per-wave partial row sums

  const int tid  = threadIdx.x;
  const int wave = tid >> 6;
  const int lane = tid & 63;
  const int quad = lane >> 4;
  const int l16  = lane & 15;
  const long rowbase = (long)blockIdx.x * 32;

  const float scale = fabsf(ds[0]) / temp[0];

  // ---- Phase 0: build A fragments from raw fp32 features (norm fused) ----
  // afrag[mt][s] = bf16( fn[rowbase+mt*16+l16][quad*8+s*32 .. +8] )
  short8 afrag[2][8];
  #pragma unroll
  for (int mt = 0; mt < 2; ++mt){
    const float* rp = feats + (rowbase + mt*16 + l16) * 256 + quad*8;
    float4 va[8], vb[8];
    float ss = 0.f;
    #pragma unroll
    for (int s = 0; s < 8; ++s){
      va[s] = *(const float4*)(rp + s*32);
      vb[s] = *(const float4*)(rp + s*32 + 4);
      ss += va[s].x*va[s].x + va[s].y*va[s].y + va[s].z*va[s].z + va[s].w*va[s].w;
      ss += vb[s].x*vb[s].x + vb[s].y*vb[s].y + vb[s].z*vb[s].z + vb[s].w*vb[s].w;
    }
    // lane holds 64 of 256 elems; quads of same l16 hold the rest
    ss += __shfl_xor(ss, 16);
    ss += __shfl_xor(ss, 32);
    const float inv = 1.0f / fmaxf(sqrtf(ss), 1e-12f);
    #pragma unroll
    for (int s = 0; s < 8; ++s){
      ushort4 lo, hi;
      lo.x = f2bf(va[s].x*inv); lo.y = f2bf(va[s].y*inv);
      lo.z = f2bf(va[s].z*inv); lo.w = f2bf(va[s].w*inv);
      hi.x = f2bf(vb[s].x*inv); hi.y = f2bf(vb[s].y*inv);
      hi.z = f2bf(vb[s].z*inv); hi.w = f2bf(vb[s].w*inv);
      U16 u;
      u.u4.x = (unsigned)lo.x | ((unsigned)lo.y << 16);
      u.u4.y = (unsigned)lo.z | ((unsigned)lo.w << 16);
      u.u4.z = (unsigned)hi.x | ((unsigned)hi.y << 16);
      u.u4.w = (unsigned)hi.z | ((unsigned)hi.w << 16);
      afrag[mt][s] = u.s8;
    }
  }

  const uint4* pbase = (const uint4*)pnw;

  // ---- Phase 1: GEMM pass accumulating masked row dist sums ----
  float rsum[2][4];
  #pragma unroll
  for (int mt = 0; mt < 2; ++mt)
    #pragma unroll
    for (int r = 0; r < 4; ++r) rsum[mt][r] = 0.f;

  for (int wt = 0; wt < 16; ++wt){
    const int t = wave*16 + wt;
    if (t == 63) continue;                       // fully padded tile
    const uint4* bp = pbase + (size_t)t*8*64 + lane;
    short8 bfrag[8];
    #pragma unroll
    for (int s = 0; s < 8; ++s){ U16 u; u.u4 = bp[s*64]; bfrag[s] = u.s8; }

    f32x4 acc[2];
    acc[0] = (f32x4){0.f,0.f,0.f,0.f};
    acc[1] = (f32x4){0.f,0.f,0.f,0.f};
    #pragma unroll
    for (int s = 0; s < 8; ++s){
      acc[0] = __builtin_amdgcn_mfma_f32_16x16x32_bf16(afrag[0][s], bfrag[s], acc[0], 0, 0, 0);
      acc[1] = __builtin_amdgcn_mfma_f32_16x16x32_bf16(afrag[1][s], bfrag[s], acc[1], 0, 0, 0);
    }
    const bool valid = (t*16 + l16) < C;
    #pragma unroll
    for (int mt = 0; mt < 2; ++mt)
      #pragma unroll
      for (int r = 0; r < 4; ++r){
        float d = sqrtf(fmaxf(1.0f - acc[mt][r], 0.0f));
        rsum[mt][r] += valid ? d : 0.0f;
      }
  }

  // reduce over the 16 l16-lanes holding each row's columns
  #pragma unroll
  for (int off = 1; off < 16; off <<= 1)
    #pragma unroll
    for (int mt = 0; mt < 2; ++mt)
      #pragma unroll
      for (int r = 0; r < 4; ++r)
        rsum[mt][r] += __shfl_xor(rsum[mt][r], off);

  if (l16 == 0){
    #pragma unroll
    for (int mt = 0; mt < 2; ++mt)
      #pragma unroll
      for (int r = 0; r < 4; ++r)
        wsum[wave][mt*16 + quad*4 + r] = rsum[mt][r];
  }
  __syncthreads();

  const float invC = 1.0f / (float)C;
  float meanv[2][4];
  #pragma unroll
  for (int mt = 0; mt < 2; ++mt)
    #pragma unroll
    for (int r = 0; r < 4; ++r){
      const int row = mt*16 + quad*4 + r;
      meanv[mt][r] = (wsum[0][row] + wsum[1][row] + wsum[2][row] + wsum[3][row]) * invC;
    }

  // ---- Phase 2: recompute GEMM, write final logits ----
  for (int wt = 0; wt < 16; ++wt){
    const int t = wave*16 + wt;
    if (t == 63) continue;
    const uint4* bp = pbase + (size_t)t*8*64 + lane;
    short8 bfrag[8];
    #pragma unroll
    for (int s = 0; s < 8; ++s){ U16 u; u.u4 = bp[s*64]; bfrag[s] = u.s8; }

    f32x4 acc[2];
    acc[0] = (f32x4){0.f,0.f,0.f,0.f};
    acc[1] = (f32x4){0.f,0.f,0.f,0.f};
    #pragma unroll
    for (int s = 0; s < 8; ++s){
      acc[0] = __builtin_amdgcn_mfma_f32_16x16x32_bf16(afrag[0][s], bfrag[s], acc[0], 0, 0, 0);
      acc[1] = __builtin_amdgcn_mfma_f32_16x16x32_bf16(afrag[1][s], bfrag[s], acc[1], 0, 0, 0);
    }
    const int col = t*16 + l16;
    if (col < C){
      #pragma unroll
      for (int mt = 0; mt < 2; ++mt)
        #pragma unroll
        for (int r = 0; r < 4; ++r){
          float d = sqrtf(fmaxf(1.0f - acc[mt][r], 0.0f));
          out[(rowbase + mt*16 + quad*4 + r) * (long)C + col] = -scale * (d + meanv[mt][r]);
        }
    }
  }
}

extern "C" void kernel_launch(void* const* d_in, const int* in_sizes, int n_in,
                              void* d_out, int out_size, void* d_ws, size_t ws_size,
                              hipStream_t stream) {
  const float* features = (const float*)d_in[0];
  const float* protos   = (const float*)d_in[1];
  const float* dscale   = (const float*)d_in[2];
  const float* temp     = (const float*)d_in[3];
  float* out = (float*)d_out;

  const int F = 256;
  const int B = in_sizes[0] / F;   // 32768
  const int C = in_sizes[1] / F;   // 1000

  unsigned short* pnw = (unsigned short*)d_ws;   // [1024 x 256] bf16, permuted

  norm_protos_kernel<<<CPAD/4, 256, 0, stream>>>(protos, pnw, C);
  fused_kernel<<<B/32, 256, 0, stream>>>(features, pnw, dscale, temp, out, C);
}

// Round 4
// 207.269 us; speedup vs baseline: 1.2037x; 1.2037x over previous
//
#include <hip/hip_runtime.h>

// DisMaxLossFirstPart: logits = -|ds|*(dist + mean_c(dist)) / temp
// dist[b,c] = sqrt(max(1 - <fn_b, pn_c>, 0)), fn/pn L2-normalized rows.
// B=32768, C=1000, F=256. fp32 in/out; bf16 MFMA internally.
//
// Round 3b: operand-swapped MFMA (A=prototypes, B=features) so lane l16 = feature
// row and quad*4+r = 4 consecutive classes -> epilogue is one coalesced float4
// store per tile. Single GEMM pass; per-lane dist strip (64 values) kept in 32
// VGPRs as packed fp16; mean via 256B LDS exchange. Fast sqrt/rcp intrinsics.

typedef __attribute__((ext_vector_type(8))) short short8;
typedef __attribute__((ext_vector_type(4))) float f32x4;
typedef __fp16 h2 __attribute__((ext_vector_type(2)));   // matches cvt_pkrtz return

union U16 { uint4 u4; short8 s8; };

static __device__ __forceinline__ unsigned short f2bf(float x){
  union { float f; unsigned u; } v; v.f = x;
  unsigned r = v.u + 0x7fffu + ((v.u >> 16) & 1u);   // RNE
  return (unsigned short)(r >> 16);
}

#define CPAD 1024          // prototype rows padded to 1024

// Normalize prototypes [C x 256] fp32 -> bf16 in fragment-ready permuted
// layout: 16B chunk index (t*8 + s)*64 + quad*16 + l16 holds
// pn[t*16 + l16][quad*8 + s*32 .. +8]. Rows >= C written as zeros.
__global__ void norm_protos_kernel(const float* __restrict__ src,
                                   unsigned short* __restrict__ dst, int C)
{
  const int wave = threadIdx.x >> 6;
  const int lane = threadIdx.x & 63;
  const int row  = blockIdx.x * 4 + wave;     // 0..1023
  const int t    = row >> 4;
  const int l16  = row & 15;
  const int s    = lane >> 3;                 // element e=4l: s = e>>5
  const int quad = (lane >> 1) & 3;           // quad = (e>>3)&3
  const int j    = (lane & 1) * 4;            // j = e&7 in {0,4}

  ushort4 o = {0, 0, 0, 0};
  if (row < C){
    const float4 v = *(const float4*)(src + row * 256 + lane * 4);
    float ss = v.x*v.x + v.y*v.y + v.z*v.z + v.w*v.w;
    #pragma unroll
    for (int off = 32; off; off >>= 1) ss += __shfl_xor(ss, off);
    const float inv = 1.0f / fmaxf(sqrtf(ss), 1e-12f);
    o.x = f2bf(v.x * inv); o.y = f2bf(v.y * inv);
    o.z = f2bf(v.z * inv); o.w = f2bf(v.w * inv);
  }
  *(ushort4*)(dst + ((size_t)((t*8 + s)*64 + quad*16 + l16))*8 + j) = o;
}

__global__ __launch_bounds__(256, 3)
void fused_kernel(const float* __restrict__ feats,
                  const unsigned short* __restrict__ pnw,
                  const float* __restrict__ ds,
                  const float* __restrict__ temp,
                  float* __restrict__ out, int C)
{
  __shared__ float wsum[16][4];   // [feature-row l16][wave]

  const int tid  = threadIdx.x;
  const int wave = tid >> 6;
  const int lane = tid & 63;
  const int quad = lane >> 4;
  const int l16  = lane & 15;
  const long rowbase = (long)blockIdx.x * 16;

  // ---- Phase 0: B-fragments (features) from raw fp32, norm fused ----
  // ffrag[s] = bf16( fn[rowbase+l16][quad*8 + s*32 .. +8] )
  short8 ffrag[8];
  {
    const float* rp = feats + (rowbase + l16) * 256 + quad*8;
    float4 va[8], vb[8];
    float ss = 0.f;
    #pragma unroll
    for (int s = 0; s < 8; ++s){
      va[s] = *(const float4*)(rp + s*32);
      vb[s] = *(const float4*)(rp + s*32 + 4);
      ss += va[s].x*va[s].x + va[s].y*va[s].y + va[s].z*va[s].z + va[s].w*va[s].w;
      ss += vb[s].x*vb[s].x + vb[s].y*vb[s].y + vb[s].z*vb[s].z + vb[s].w*vb[s].w;
    }
    ss += __shfl_xor(ss, 16);
    ss += __shfl_xor(ss, 32);
    const float inv = __builtin_amdgcn_rcpf(__builtin_amdgcn_sqrtf(fmaxf(ss, 1e-24f)));
    #pragma unroll
    for (int s = 0; s < 8; ++s){
      U16 u;
      u.u4.x = (unsigned)f2bf(va[s].x*inv) | ((unsigned)f2bf(va[s].y*inv) << 16);
      u.u4.y = (unsigned)f2bf(va[s].z*inv) | ((unsigned)f2bf(va[s].w*inv) << 16);
      u.u4.z = (unsigned)f2bf(vb[s].x*inv) | ((unsigned)f2bf(vb[s].y*inv) << 16);
      u.u4.w = (unsigned)f2bf(vb[s].z*inv) | ((unsigned)f2bf(vb[s].w*inv) << 16);
      ffrag[s] = u.s8;
    }
  }

  // ---- Single GEMM pass: wave owns classes [wave*256, +256) in 16 tiles ----
  const uint4* tp = (const uint4*)pnw + (size_t)(wave*16)*512 + lane;

  h2 dd[16][2];     // per-lane dist strip, fp16-packed (32 VGPRs)
  float rsum = 0.f;

  #pragma unroll
  for (int wt = 0; wt < 16; ++wt){
    const uint4* bp = tp + (size_t)wt*512;
    short8 pfrag[8];
    #pragma unroll
    for (int s = 0; s < 8; ++s){ U16 u; u.u4 = bp[s*64]; pfrag[s] = u.s8; }

    f32x4 acc = (f32x4){0.f, 0.f, 0.f, 0.f};
    #pragma unroll
    for (int s = 0; s < 8; ++s)
      acc = __builtin_amdgcn_mfma_f32_16x16x32_bf16(pfrag[s], ffrag[s], acc, 0, 0, 0);

    float d0 = __builtin_amdgcn_sqrtf(fmaxf(1.0f - acc[0], 0.0f));
    float d1 = __builtin_amdgcn_sqrtf(fmaxf(1.0f - acc[1], 0.0f));
    float d2 = __builtin_amdgcn_sqrtf(fmaxf(1.0f - acc[2], 0.0f));
    float d3 = __builtin_amdgcn_sqrtf(fmaxf(1.0f - acc[3], 0.0f));

    const int cls = wave*256 + wt*16 + quad*4;   // C%4==0: all-or-nothing
    rsum += (cls < C) ? (d0 + d1 + d2 + d3) : 0.0f;

    dd[wt][0] = __builtin_amdgcn_cvt_pkrtz(d0, d1);
    dd[wt][1] = __builtin_amdgcn_cvt_pkrtz(d2, d3);
  }

  // ---- Row mean: reduce over quads, exchange across waves ----
  rsum += __shfl_xor(rsum, 16);
  rsum += __shfl_xor(rsum, 32);
  if (quad == 0) wsum[l16][wave] = rsum;
  __syncthreads();

  const float4 wv = *(const float4*)&wsum[l16][0];
  const float mean = (wv.x + wv.y + wv.z + wv.w) / (float)C;
  const float nscale = -fabsf(ds[0]) / temp[0];
  const float bias = nscale * mean;

  // ---- Epilogue: coalesced float4 stores ----
  float* orow = out + (rowbase + l16) * (size_t)C;
  #pragma unroll
  for (int wt = 0; wt < 16; ++wt){
    const int cls = wave*256 + wt*16 + quad*4;
    if (cls < C){
      float4 o;
      o.x = fmaf(nscale, (float)dd[wt][0][0], bias);
      o.y = fmaf(nscale, (float)dd[wt][0][1], bias);
      o.z = fmaf(nscale, (float)dd[wt][1][0], bias);
      o.w = fmaf(nscale, (float)dd[wt][1][1], bias);
      *(float4*)(orow + cls) = o;
    }
  }
}

extern "C" void kernel_launch(void* const* d_in, const int* in_sizes, int n_in,
                              void* d_out, int out_size, void* d_ws, size_t ws_size,
                              hipStream_t stream) {
  const float* features = (const float*)d_in[0];
  const float* protos   = (const float*)d_in[1];
  const float* dscale   = (const float*)d_in[2];
  const float* temp     = (const float*)d_in[3];
  float* out = (float*)d_out;

  const int F = 256;
  const int B = in_sizes[0] / F;   // 32768
  const int C = in_sizes[1] / F;   // 1000

  unsigned short* pnw = (unsigned short*)d_ws;   // [1024 x 256] bf16, permuted

  norm_protos_kernel<<<CPAD/4, 256, 0, stream>>>(protos, pnw, C);
  fused_kernel<<<B/16, 256, 0, stream>>>(features, pnw, dscale, temp, out, C);
}